// Round 1
// baseline (1358.535 us; speedup 1.0000x reference)
//
#include <hip/hip_runtime.h>

typedef unsigned short u16;
typedef __attribute__((ext_vector_type(8))) short v8s;
typedef __attribute__((ext_vector_type(4))) float f32x4;

#define NROW 128
#define W1OFF 0
#define W2OFF 8192
#define W3OFF 73728
#define W4OFF 139264
#define TOTW  143360

__device__ __forceinline__ u16 f2bf(float f) {
  unsigned int u = __float_as_uint(f);
  if ((u & 0x7f800000u) == 0x7f800000u) return (u16)(u >> 16);  // inf/nan passthrough
  unsigned int r = u + 0x7fffu + ((u >> 16) & 1u);              // RNE
  return (u16)(r >> 16);
}
__device__ __forceinline__ float bf2f(u16 h) {
  return __uint_as_float(((unsigned int)h) << 16);
}
__device__ __forceinline__ float silu_f(float x) {
  return x * __builtin_amdgcn_rcpf(1.0f + __expf(-x));
}

// XOR-swizzled index into the 128x256 bf16 activation tile (kills the
// 512B-row-stride bank conflict on ds_read_b128 A-fragment loads).
#define HAIDX(row, col) (((row) << 8) + ((col) ^ (((row) & 7) << 3)))

// ---------------------------------------------------------------------------
// Prep: convert weights to bf16 and lay them out in MFMA B-fragment-linear
// order. For 16x16x32: lane l supplies B[(l>>4)*8 + j][l&15], j=0..7.
// W1 is padded K 6->32 with rows 6..11 duplicating rows 0..5 (hi/lo split
// of the input consumes the duplicate), rest zero. W4 padded N 4->16.
// ---------------------------------------------------------------------------
__global__ void prep_kernel(const float* __restrict__ W1, const float* __restrict__ W2,
                            const float* __restrict__ W3, const float* __restrict__ W4,
                            u16* __restrict__ Wf) {
  int e = blockIdx.x * 256 + threadIdx.x;
  if (e >= TOTW) return;
  float val;
  if (e < W2OFF) {                       // W1 frags: [nt][lane][j], 16 nt
    int nt = e >> 9, r = e & 511, l = r >> 3, j = r & 7;
    int k = ((l >> 4) << 3) + j, n = (nt << 4) + (l & 15);
    val = (k < 6) ? W1[k * 256 + n] : ((k < 12) ? W1[(k - 6) * 256 + n] : 0.0f);
  } else if (e < W3OFF) {                // W2 frags: [(nt*8+ks)][lane][j]
    int e2 = e - W2OFF;
    int blk = e2 >> 9, r = e2 & 511, l = r >> 3, j = r & 7;
    int nt = blk >> 3, ks = blk & 7;
    int k = (ks << 5) + ((l >> 4) << 3) + j, n = (nt << 4) + (l & 15);
    val = W2[k * 256 + n];
  } else if (e < W4OFF) {                // W3 frags
    int e2 = e - W3OFF;
    int blk = e2 >> 9, r = e2 & 511, l = r >> 3, j = r & 7;
    int nt = blk >> 3, ks = blk & 7;
    int k = (ks << 5) + ((l >> 4) << 3) + j, n = (nt << 4) + (l & 15);
    val = W3[k * 256 + n];
  } else {                               // W4 frags: [ks][lane][j], N padded to 16
    int e2 = e - W4OFF;
    int ks = e2 >> 9, r = e2 & 511, l = r >> 3, j = r & 7;
    int k = (ks << 5) + ((l >> 4) << 3) + j, n = l & 15;
    val = (n < 4) ? W4[k * 4 + n] : 0.0f;
  }
  Wf[e] = f2bf(val);
}

// ---------------------------------------------------------------------------
// Main fused kernel. 512 threads = 8 waves; each wave owns a 16-row M-tile.
// hA (activations) is wave-private. W2/W3 K-slices (16KB) are LDS-staged,
// double-buffered: issue global loads early, ds_write after MFMA, one
// barrier per K-slice keeps the rolling pipeline correct.
// ---------------------------------------------------------------------------
__global__ __launch_bounds__(512, 2) void pinn_main(
    const float* __restrict__ sdz, const float* __restrict__ zf,
    const u16* __restrict__ Wf,
    const float* __restrict__ b1, const float* __restrict__ b2,
    const float* __restrict__ b3, const float* __restrict__ b4,
    float* __restrict__ out) {
  __shared__ __align__(16) u16 hA[NROW * 256];   // 64 KB activations (bf16, swizzled)
  __shared__ __align__(16) u16 A1[NROW * 32];    // 8 KB layer-1 input (hi/lo split, zero-padded)
  __shared__ __align__(16) u16 Ws[2][8192];      // 2 x 16 KB weight K-slice buffers
  __shared__ float stS[NROW * 4];
  __shared__ float qopS[NROW], dzS[NROW], fracS[NROW];
  __shared__ int nfS[NROW];
  __shared__ float bS[3][256];
  __shared__ float b4S[4];
  __shared__ int s_maxnf;

  const int t = threadIdx.x;
  const int lane = t & 63;
  const int wv = t >> 6;
  const int m = lane & 15;      // C col / A row within tile
  const int q = lane >> 4;      // k-block / C row-block
  const int r0 = wv << 4;       // wave's first row
  const int row0 = blockIdx.x * NROW;
  const f32x4 ZERO4 = {0.0f, 0.0f, 0.0f, 0.0f};

  for (int i = t; i < NROW * 32; i += 512) A1[i] = 0;   // pad cols stay zero forever
  if (t < 256) { bS[0][t] = b1[t]; bS[1][t] = b2[t]; bS[2][t] = b3[t]; }
  if (t < 4) b4S[t] = b4[t];
  if (t == 0) s_maxnf = 0;
  if (t < NROW) {
    const float* p = sdz + (size_t)(row0 + t) * 6;
    stS[t * 4 + 0] = p[0]; stS[t * 4 + 1] = p[1];
    stS[t * 4 + 2] = p[2]; stS[t * 4 + 3] = p[3];
    qopS[t] = p[4];
    dzS[t] = p[5] * 0.125f;                 // dz_total / N_STEPS (exact)
    float cs = zf[row0 + t] * 8.0f;
    float nf = floorf(cs);
    nfS[t] = (int)nf;
    fracS[t] = cs - nf;
  }
  __syncthreads();
  if (t < NROW) atomicMax(&s_maxnf, nfS[t]);

  // stage W2 slice 0 (pipeline prologue)
  const int nt_s = t >> 5;             // staging: thread's N-tile
  const int p_s = (t & 31) << 4;       // 32B piece within the 512-ushort chunk
  {
    const int4* g = (const int4*)(Wf + W2OFF + (nt_s * 8) * 512 + p_s);
    int4 a0 = g[0], a1 = g[1];
    int4* d = (int4*)&Ws[0][nt_s * 512 + p_s];
    d[0] = a0; d[1] = a1;
  }
  __syncthreads();
  const int maxnf = s_maxnf;
  int buf = 0;

  // step 0..maxnf-1 = full steps (mask n_full>step), step 8 = partial step
  for (int step = 0; step <= 8; ++step) {
    if (step < 8 && step >= maxnf) continue;   // no row active in this step
    const bool partial = (step == 8);

    // ---- build A1 rows (wave-private; lane l -> row r0+(l&15), 3 cols per lane) ----
    {
      const int row = r0 + m;
      const float dzv = partial ? fracS[row] * dzS[row] : dzS[row];
      #pragma unroll
      for (int i = 0; i < 3; ++i) {
        const int c = q * 3 + i;                   // cols 0..11
        const int base = (c < 6) ? c : (c - 6);
        float x = (base < 4) ? stS[row * 4 + base]
                             : ((base == 4) ? qopS[row] : dzv);
        u16 hi = f2bf(x);
        A1[row * 32 + c] = (c < 6) ? hi : f2bf(x - bf2f(hi));  // hi | lo split
      }
    }
    __syncthreads();

    // ---- L1: h1 = silu(A1 @ W1f + b1), K=32 (hi/lo), one MFMA per N-tile ----
    {
      const v8s a = *(const v8s*)&A1[(r0 + m) * 32 + q * 8];
      f32x4 acc1[16];
      #pragma unroll
      for (int nt = 0; nt < 16; ++nt) {
        const v8s b = *(const v8s*)(Wf + W1OFF + nt * 512 + lane * 8);
        acc1[nt] = __builtin_amdgcn_mfma_f32_16x16x32_bf16(a, b, ZERO4, 0, 0, 0);
      }
      #pragma unroll
      for (int nt = 0; nt < 16; ++nt) {
        const int col = nt * 16 + m;
        const float bias = bS[0][col];
        #pragma unroll
        for (int r = 0; r < 4; ++r) {
          const int row = r0 + q * 4 + r;
          hA[HAIDX(row, col)] = f2bf(silu_f(acc1[nt][r] + bias));
        }
      }
    }
    __syncthreads();

    // ---- L2 and L3: 256x256 GEMMs, LDS-staged double-buffered weight slices ----
    for (int layer = 0; layer < 2; ++layer) {
      const int thisOff = (layer == 0) ? W2OFF : W3OFF;
      const int otherOff = (layer == 0) ? W3OFF : W2OFF;  // next layer / next step's W2
      f32x4 acc[16];
      #pragma unroll
      for (int nt = 0; nt < 16; ++nt) acc[nt] = ZERO4;
      for (int ks = 0; ks < 8; ++ks) {
        // issue next slice's global loads early (latency hides under MFMAs)
        const int nxtOff = (ks < 7) ? thisOff : otherOff;
        const int nks = (ks < 7) ? (ks + 1) : 0;
        const int4* g = (const int4*)(Wf + nxtOff + (nt_s * 8 + nks) * 512 + p_s);
        int4 s0 = g[0], s1 = g[1];
        // A fragment (wave-private rows, swizzled)
        const int arow = r0 + m;
        const v8s a = *(const v8s*)&hA[HAIDX(arow, ks * 32 + q * 8)];
        #pragma unroll
        for (int nt = 0; nt < 16; ++nt) {
          const v8s b = *(const v8s*)&Ws[buf][nt * 512 + lane * 8];
          acc[nt] = __builtin_amdgcn_mfma_f32_16x16x32_bf16(a, b, acc[nt], 0, 0, 0);
        }
        // write staged slice into the other buffer, then one barrier per slice
        int4* d = (int4*)&Ws[buf ^ 1][nt_s * 512 + p_s];
        d[0] = s0; d[1] = s1;
        __syncthreads();
        buf ^= 1;
      }
      // epilogue: silu + bias, write back over hA (wave-private rows)
      #pragma unroll
      for (int nt = 0; nt < 16; ++nt) {
        const int col = nt * 16 + m;
        const float bias = bS[layer + 1][col];
        #pragma unroll
        for (int r = 0; r < 4; ++r) {
          const int row = r0 + q * 4 + r;
          hA[HAIDX(row, col)] = f2bf(silu_f(acc[nt][r] + bias));
        }
      }
      __syncthreads();
    }

    // ---- L4 (N padded 4->16) + masked state update ----
    {
      f32x4 acc4 = ZERO4;
      #pragma unroll
      for (int ks = 0; ks < 8; ++ks) {
        const int arow = r0 + m;
        const v8s a = *(const v8s*)&hA[HAIDX(arow, ks * 32 + q * 8)];
        const v8s b = *(const v8s*)(Wf + W4OFF + ks * 512 + lane * 8);
        acc4 = __builtin_amdgcn_mfma_f32_16x16x32_bf16(a, b, acc4, 0, 0, 0);
      }
      if (m < 4) {
        #pragma unroll
        for (int r = 0; r < 4; ++r) {
          const int row = r0 + q * 4 + r;
          const bool act = partial ? (fracS[row] > 1e-6f) : (nfS[row] > step);
          if (act) stS[row * 4 + m] += acc4[r] + b4S[m];
        }
      }
    }
    __syncthreads();
  }

  // coalesced f32 output write: (B,4) row-major
  out[(size_t)row0 * 4 + t] = stS[t];
}

extern "C" void kernel_launch(void* const* d_in, const int* in_sizes, int n_in,
                              void* d_out, int out_size, void* d_ws, size_t ws_size,
                              hipStream_t stream) {
  const float* sdz = (const float*)d_in[0];
  const float* zfr = (const float*)d_in[1];
  const float* W1 = (const float*)d_in[2];
  const float* b1 = (const float*)d_in[3];
  const float* W2 = (const float*)d_in[4];
  const float* b2 = (const float*)d_in[5];
  const float* W3 = (const float*)d_in[6];
  const float* b3 = (const float*)d_in[7];
  const float* W4 = (const float*)d_in[8];
  const float* b4 = (const float*)d_in[9];
  u16* Wf = (u16*)d_ws;   // 286720 bytes of bf16 fragment-ordered weights

  prep_kernel<<<TOTW / 256, 256, 0, stream>>>(W1, W2, W3, W4, Wf);

  const int B = in_sizes[1];          // 262144
  const int grid = B / NROW;          // 2048
  pinn_main<<<grid, 512, 0, stream>>>(sdz, zfr, Wf, b1, b2, b3, b4, (float*)d_out);
}